// Round 1
// baseline (398.390 us; speedup 1.0000x reference)
//
#include <hip/hip_runtime.h>
#include <stdint.h>

#define N_NODES 100000
#define N_EDGES 1600000
#define HIDDEN  64
#define SLOPE   0.01f

// K1: per-node attention scores s_i = x.w_i, s_j = x.w_j (wave per node, lane = dim)
//     + zero the per-node edge counters (ws is re-poisoned before every call).
__global__ void __launch_bounds__(256) k_scores(const float* __restrict__ x,
                                                const float* __restrict__ w_i,
                                                const float* __restrict__ w_j,
                                                float* __restrict__ s_i,
                                                float* __restrict__ s_j,
                                                int* __restrict__ counts) {
    int tid = threadIdx.x;
    int gt  = blockIdx.x * 256 + tid;
    if (gt < N_NODES) counts[gt] = 0;
    int node = blockIdx.x * 4 + (tid >> 6);
    int lane = tid & 63;
    if (node >= N_NODES) return;
    float v = x[node * HIDDEN + lane];
    float a = v * w_i[lane];
    float b = v * w_j[lane];
    for (int off = 32; off > 0; off >>= 1) {
        a += __shfl_xor(a, off, 64);
        b += __shfl_xor(b, off, 64);
    }
    if (lane == 0) { s_i[node] = a; s_j[node] = b; }
}

// K2: histogram of destination degrees
__global__ void __launch_bounds__(256) k_count(const int* __restrict__ dst,
                                               int* __restrict__ counts) {
    int t = blockIdx.x * 256 + threadIdx.x;
    if (t < N_EDGES) atomicAdd(&counts[dst[t]], 1);
}

// K3a: per-tile exclusive scan (tile = 256), emit tile totals
__global__ void __launch_bounds__(256) k_scan1(const int* __restrict__ counts,
                                               int* __restrict__ offs,
                                               int* __restrict__ bsum) {
    __shared__ int sh[256];
    int tid = threadIdx.x;
    int idx = blockIdx.x * 256 + tid;
    int v = (idx < N_NODES) ? counts[idx] : 0;
    sh[tid] = v;
    __syncthreads();
    for (int off = 1; off < 256; off <<= 1) {
        int t = (tid >= off) ? sh[tid - off] : 0;
        __syncthreads();
        sh[tid] += t;
        __syncthreads();
    }
    if (idx < N_NODES) offs[idx] = sh[tid] - v;   // exclusive
    if (tid == 255) bsum[blockIdx.x] = sh[tid];   // tile total
}

// K3b: scan the tile totals (single block; nb <= 512)
__global__ void __launch_bounds__(512) k_scan2(const int* __restrict__ bsum,
                                               int* __restrict__ bsum2, int nb) {
    __shared__ int sh[512];
    int tid = threadIdx.x;
    int v = (tid < nb) ? bsum[tid] : 0;
    sh[tid] = v;
    __syncthreads();
    for (int off = 1; off < 512; off <<= 1) {
        int t = (tid >= off) ? sh[tid - off] : 0;
        __syncthreads();
        sh[tid] += t;
        __syncthreads();
    }
    if (tid < nb) bsum2[tid] = sh[tid] - v;       // exclusive
}

// K3c: add tile bases; init scatter cursors
__global__ void __launch_bounds__(256) k_scan3(int* __restrict__ offs,
                                               const int* __restrict__ bsum2,
                                               int* __restrict__ cursor) {
    int idx = blockIdx.x * 256 + threadIdx.x;
    if (idx < N_NODES) {
        int o = offs[idx] + bsum2[blockIdx.x];
        offs[idx] = o;
        cursor[idx] = o;
    }
}

// K4: per-edge weight (leaky_relu + exp, no max-subtraction needed numerically)
//     and bucket {src, w} into dst-CSR via cursor atomics. 8B packed store.
__global__ void __launch_bounds__(256) k_scatter(const int* __restrict__ srcs,
                                                 const int* __restrict__ dsts,
                                                 const float* __restrict__ s_i,
                                                 const float* __restrict__ s_j,
                                                 int* __restrict__ cursor,
                                                 uint64_t* __restrict__ pairs) {
    int t = blockIdx.x * 256 + threadIdx.x;
    if (t >= N_EDGES) return;
    int src = srcs[t];
    int dst = dsts[t];
    float e = s_i[dst] + s_j[src];
    e = (e > 0.f) ? e : SLOPE * e;
    float w = __expf(e);
    int pos = atomicAdd(&cursor[dst], 1);
    pairs[pos] = ((uint64_t)__float_as_uint(w) << 32) | (uint32_t)src;
}

// K5: wave per node, lane = hidden dim. denom + weighted x-gather accumulate
//     in registers; fused divide + relu on the way out.
__global__ void __launch_bounds__(256) k_aggregate(const float* __restrict__ x,
                                                   const uint64_t* __restrict__ pairs,
                                                   const int* __restrict__ offs,
                                                   const int* __restrict__ counts,
                                                   float* __restrict__ out) {
    int tid  = threadIdx.x;
    int node = blockIdx.x * 4 + (tid >> 6);
    int lane = tid & 63;
    if (node >= N_NODES) return;
    int start = offs[node];
    int cnt   = counts[node];
    float acc = 0.f, denom = 0.f;
    for (int i = 0; i < cnt; ++i) {
        uint64_t p = pairs[start + i];           // broadcast load (same addr all lanes)
        int   src = (int)(uint32_t)(p & 0xffffffffu);
        float w   = __uint_as_float((uint32_t)(p >> 32));
        denom += w;
        acc   += w * x[src * HIDDEN + lane];     // coalesced 256B per edge
    }
    float r = (cnt > 0) ? (acc / denom) : 0.f;   // empty segment -> 0 (matches ref)
    out[node * HIDDEN + lane] = fmaxf(r, 0.f);
}

extern "C" void kernel_launch(void* const* d_in, const int* in_sizes, int n_in,
                              void* d_out, int out_size, void* d_ws, size_t ws_size,
                              hipStream_t stream) {
    const float* x   = (const float*)d_in[0];
    const int*   ei  = (const int*)d_in[1];   // [2, E] flat: row0 = ej (src), row1 = ei (dst)
    const float* w_i = (const float*)d_in[2];
    const float* w_j = (const float*)d_in[3];
    float* out = (float*)d_out;

    char* p = (char*)d_ws;
    float*    s_i    = (float*)p;      p += (size_t)N_NODES * 4;   // 400000
    float*    s_j    = (float*)p;      p += (size_t)N_NODES * 4;
    int*      counts = (int*)p;        p += (size_t)N_NODES * 4;
    int*      offs   = (int*)p;        p += (size_t)N_NODES * 4;
    int*      cursor = (int*)p;        p += (size_t)N_NODES * 4;
    int*      bsum   = (int*)p;        p += 4096;
    int*      bsum2  = (int*)p;        p += 4096;
    uint64_t* pairs  = (uint64_t*)p;   // E * 8 bytes

    const int* srcs = ei;              // edge_index[0]
    const int* dsts = ei + N_EDGES;    // edge_index[1]

    int nb = (N_NODES + 255) / 256;    // 391 scan tiles

    k_scores   <<<(N_NODES + 3) / 4, 256, 0, stream>>>(x, w_i, w_j, s_i, s_j, counts);
    k_count    <<<(N_EDGES + 255) / 256, 256, 0, stream>>>(dsts, counts);
    k_scan1    <<<nb, 256, 0, stream>>>(counts, offs, bsum);
    k_scan2    <<<1, 512, 0, stream>>>(bsum, bsum2, nb);
    k_scan3    <<<nb, 256, 0, stream>>>(offs, bsum2, cursor);
    k_scatter  <<<(N_EDGES + 255) / 256, 256, 0, stream>>>(srcs, dsts, s_i, s_j, cursor, pairs);
    k_aggregate<<<(N_NODES + 3) / 4, 256, 0, stream>>>(x, pairs, offs, counts, out);
}

// Round 2
// 307.733 us; speedup vs baseline: 1.2946x; 1.2946x over previous
//
#include <hip/hip_runtime.h>
#include <stdint.h>

#define N_NODES 100000
#define N_EDGES 1600000
#define HIDDEN  64
#define SLOPE   0.01f

// K1: per-node attention scores s_i = x.w_i, s_j = x.w_j (wave per node, lane = dim)
//     + zero the per-node edge counters (ws is re-poisoned before every call).
__global__ void __launch_bounds__(256) k_scores(const float* __restrict__ x,
                                                const float* __restrict__ w_i,
                                                const float* __restrict__ w_j,
                                                float* __restrict__ s_i,
                                                float* __restrict__ s_j,
                                                int* __restrict__ counts) {
    int tid = threadIdx.x;
    int gt  = blockIdx.x * 256 + tid;
    if (gt < N_NODES) counts[gt] = 0;
    int node = blockIdx.x * 4 + (tid >> 6);
    int lane = tid & 63;
    if (node >= N_NODES) return;
    float v = x[node * HIDDEN + lane];
    float a = v * w_i[lane];
    float b = v * w_j[lane];
    for (int off = 32; off > 0; off >>= 1) {
        a += __shfl_xor(a, off, 64);
        b += __shfl_xor(b, off, 64);
    }
    if (lane == 0) { s_i[node] = a; s_j[node] = b; }
}

// K2: histogram of destination degrees
__global__ void __launch_bounds__(256) k_count(const int* __restrict__ dst,
                                               int* __restrict__ counts) {
    int t = blockIdx.x * 256 + threadIdx.x;
    if (t < N_EDGES) atomicAdd(&counts[dst[t]], 1);
}

// K3a: per-tile exclusive scan (tile = 256), emit tile totals
__global__ void __launch_bounds__(256) k_scan1(const int* __restrict__ counts,
                                               int* __restrict__ offs,
                                               int* __restrict__ bsum) {
    __shared__ int sh[256];
    int tid = threadIdx.x;
    int idx = blockIdx.x * 256 + tid;
    int v = (idx < N_NODES) ? counts[idx] : 0;
    sh[tid] = v;
    __syncthreads();
    for (int off = 1; off < 256; off <<= 1) {
        int t = (tid >= off) ? sh[tid - off] : 0;
        __syncthreads();
        sh[tid] += t;
        __syncthreads();
    }
    if (idx < N_NODES) offs[idx] = sh[tid] - v;   // exclusive
    if (tid == 255) bsum[blockIdx.x] = sh[tid];   // tile total
}

// K3b: scan the tile totals (single block; nb <= 512)
__global__ void __launch_bounds__(512) k_scan2(const int* __restrict__ bsum,
                                               int* __restrict__ bsum2, int nb) {
    __shared__ int sh[512];
    int tid = threadIdx.x;
    int v = (tid < nb) ? bsum[tid] : 0;
    sh[tid] = v;
    __syncthreads();
    for (int off = 1; off < 512; off <<= 1) {
        int t = (tid >= off) ? sh[tid - off] : 0;
        __syncthreads();
        sh[tid] += t;
        __syncthreads();
    }
    if (tid < nb) bsum2[tid] = sh[tid] - v;       // exclusive
}

// K3c: add tile bases; init scatter cursors
__global__ void __launch_bounds__(256) k_scan3(int* __restrict__ offs,
                                               const int* __restrict__ bsum2,
                                               int* __restrict__ cursor) {
    int idx = blockIdx.x * 256 + threadIdx.x;
    if (idx < N_NODES) {
        int o = offs[idx] + bsum2[blockIdx.x];
        offs[idx] = o;
        cursor[idx] = o;
    }
}

// K4: per-edge weight (leaky_relu + exp, no max-subtraction needed numerically)
//     and bucket {src, w} into dst-CSR via cursor atomics. 8B packed store.
__global__ void __launch_bounds__(256) k_scatter(const int* __restrict__ srcs,
                                                 const int* __restrict__ dsts,
                                                 const float* __restrict__ s_i,
                                                 const float* __restrict__ s_j,
                                                 int* __restrict__ cursor,
                                                 uint64_t* __restrict__ pairs) {
    int t = blockIdx.x * 256 + threadIdx.x;
    if (t >= N_EDGES) return;
    int src = srcs[t];
    int dst = dsts[t];
    float e = s_i[dst] + s_j[src];
    e = (e > 0.f) ? e : SLOPE * e;
    float w = __expf(e);
    int pos = atomicAdd(&cursor[dst], 1);
    pairs[pos] = ((uint64_t)__float_as_uint(w) << 32) | (uint32_t)src;
}

// K5: wave per node, lane = hidden dim. Edge loop unrolled x8/x4 with
//     independent accumulators so up to 8 x-row gathers are in flight
//     (R1 showed this kernel latency-bound: 17% HBM, 16% VALU).
__global__ void __launch_bounds__(256) k_aggregate(const float* __restrict__ x,
                                                   const uint64_t* __restrict__ pairs,
                                                   const int* __restrict__ offs,
                                                   const int* __restrict__ counts,
                                                   float* __restrict__ out) {
    int tid  = threadIdx.x;
    int node = blockIdx.x * 4 + (tid >> 6);
    int lane = tid & 63;
    if (node >= N_NODES) return;
    int start = offs[node];
    int cnt   = counts[node];
    const uint64_t* pp = pairs + start;

    float acc0 = 0.f, acc1 = 0.f, acc2 = 0.f, acc3 = 0.f;
    float acc4 = 0.f, acc5 = 0.f, acc6 = 0.f, acc7 = 0.f;
    float den  = 0.f;
    int i = 0;

    for (; i + 8 <= cnt; i += 8) {
        uint64_t p0 = pp[i+0], p1 = pp[i+1], p2 = pp[i+2], p3 = pp[i+3];
        uint64_t p4 = pp[i+4], p5 = pp[i+5], p6 = pp[i+6], p7 = pp[i+7];
        float w0 = __uint_as_float((uint32_t)(p0 >> 32));
        float w1 = __uint_as_float((uint32_t)(p1 >> 32));
        float w2 = __uint_as_float((uint32_t)(p2 >> 32));
        float w3 = __uint_as_float((uint32_t)(p3 >> 32));
        float w4 = __uint_as_float((uint32_t)(p4 >> 32));
        float w5 = __uint_as_float((uint32_t)(p5 >> 32));
        float w6 = __uint_as_float((uint32_t)(p6 >> 32));
        float w7 = __uint_as_float((uint32_t)(p7 >> 32));
        float x0 = x[(uint32_t)p0 * HIDDEN + lane];
        float x1 = x[(uint32_t)p1 * HIDDEN + lane];
        float x2 = x[(uint32_t)p2 * HIDDEN + lane];
        float x3 = x[(uint32_t)p3 * HIDDEN + lane];
        float x4 = x[(uint32_t)p4 * HIDDEN + lane];
        float x5 = x[(uint32_t)p5 * HIDDEN + lane];
        float x6 = x[(uint32_t)p6 * HIDDEN + lane];
        float x7 = x[(uint32_t)p7 * HIDDEN + lane];
        den += (w0 + w1 + w2 + w3) + (w4 + w5 + w6 + w7);
        acc0 = fmaf(w0, x0, acc0); acc1 = fmaf(w1, x1, acc1);
        acc2 = fmaf(w2, x2, acc2); acc3 = fmaf(w3, x3, acc3);
        acc4 = fmaf(w4, x4, acc4); acc5 = fmaf(w5, x5, acc5);
        acc6 = fmaf(w6, x6, acc6); acc7 = fmaf(w7, x7, acc7);
    }
    if (i + 4 <= cnt) {
        uint64_t p0 = pp[i+0], p1 = pp[i+1], p2 = pp[i+2], p3 = pp[i+3];
        float w0 = __uint_as_float((uint32_t)(p0 >> 32));
        float w1 = __uint_as_float((uint32_t)(p1 >> 32));
        float w2 = __uint_as_float((uint32_t)(p2 >> 32));
        float w3 = __uint_as_float((uint32_t)(p3 >> 32));
        float x0 = x[(uint32_t)p0 * HIDDEN + lane];
        float x1 = x[(uint32_t)p1 * HIDDEN + lane];
        float x2 = x[(uint32_t)p2 * HIDDEN + lane];
        float x3 = x[(uint32_t)p3 * HIDDEN + lane];
        den += (w0 + w1) + (w2 + w3);
        acc0 = fmaf(w0, x0, acc0); acc1 = fmaf(w1, x1, acc1);
        acc2 = fmaf(w2, x2, acc2); acc3 = fmaf(w3, x3, acc3);
        i += 4;
    }
    for (; i < cnt; ++i) {
        uint64_t p = pp[i];
        float w = __uint_as_float((uint32_t)(p >> 32));
        den += w;
        acc0 = fmaf(w, x[(uint32_t)p * HIDDEN + lane], acc0);
    }

    float acc = ((acc0 + acc1) + (acc2 + acc3)) + ((acc4 + acc5) + (acc6 + acc7));
    float r = (cnt > 0) ? (acc / den) : 0.f;     // empty segment -> 0 (matches ref)
    out[node * HIDDEN + lane] = fmaxf(r, 0.f);
}

extern "C" void kernel_launch(void* const* d_in, const int* in_sizes, int n_in,
                              void* d_out, int out_size, void* d_ws, size_t ws_size,
                              hipStream_t stream) {
    const float* x   = (const float*)d_in[0];
    const int*   ei  = (const int*)d_in[1];   // [2, E] flat: row0 = ej (src), row1 = ei (dst)
    const float* w_i = (const float*)d_in[2];
    const float* w_j = (const float*)d_in[3];
    float* out = (float*)d_out;

    char* p = (char*)d_ws;
    float*    s_i    = (float*)p;      p += (size_t)N_NODES * 4;   // 400000
    float*    s_j    = (float*)p;      p += (size_t)N_NODES * 4;
    int*      counts = (int*)p;        p += (size_t)N_NODES * 4;
    int*      offs   = (int*)p;        p += (size_t)N_NODES * 4;
    int*      cursor = (int*)p;        p += (size_t)N_NODES * 4;
    int*      bsum   = (int*)p;        p += 4096;
    int*      bsum2  = (int*)p;        p += 4096;
    uint64_t* pairs  = (uint64_t*)p;   // E * 8 bytes

    const int* srcs = ei;              // edge_index[0]
    const int* dsts = ei + N_EDGES;    // edge_index[1]

    int nb = (N_NODES + 255) / 256;    // 391 scan tiles

    k_scores   <<<(N_NODES + 3) / 4, 256, 0, stream>>>(x, w_i, w_j, s_i, s_j, counts);
    k_count    <<<(N_EDGES + 255) / 256, 256, 0, stream>>>(dsts, counts);
    k_scan1    <<<nb, 256, 0, stream>>>(counts, offs, bsum);
    k_scan2    <<<1, 512, 0, stream>>>(bsum, bsum2, nb);
    k_scan3    <<<nb, 256, 0, stream>>>(offs, bsum2, cursor);
    k_scatter  <<<(N_EDGES + 255) / 256, 256, 0, stream>>>(srcs, dsts, s_i, s_j, cursor, pairs);
    k_aggregate<<<(N_NODES + 3) / 4, 256, 0, stream>>>(x, pairs, offs, counts, out);
}

// Round 3
// 236.359 us; speedup vs baseline: 1.6855x; 1.3020x over previous
//
#include <hip/hip_runtime.h>
#include <stdint.h>

#define N_NODES 100000
#define N_EDGES 1600000
#define HIDDEN  64
#define SLOPE   0.01f
#define NBUCK   391     // ceil(N_NODES/256): coarse buckets of 256 dst nodes
#define ECHUNK  4096    // edges per partition block
#define CAP     3072    // LDS staging cap per 64-node sub-bucket (avg ~1024, sd 32)

// K1: per-node attention scores s_i = x.w_i, s_j = x.w_j (wave per node, lane = dim)
//     + zero the per-bucket edge counters (ws is re-poisoned before every call).
__global__ void __launch_bounds__(256) k_scores(const float* __restrict__ x,
                                                const float* __restrict__ w_i,
                                                const float* __restrict__ w_j,
                                                float* __restrict__ s_i,
                                                float* __restrict__ s_j,
                                                int* __restrict__ bcnt) {
    int tid = threadIdx.x;
    int gt  = blockIdx.x * 256 + tid;
    if (gt < NBUCK) bcnt[gt] = 0;
    int node = blockIdx.x * 4 + (tid >> 6);
    int lane = tid & 63;
    if (node >= N_NODES) return;
    float v = x[node * HIDDEN + lane];
    float a = v * w_i[lane];
    float b = v * w_j[lane];
    for (int off = 32; off > 0; off >>= 1) {
        a += __shfl_xor(a, off, 64);
        b += __shfl_xor(b, off, 64);
    }
    if (lane == 0) { s_i[node] = a; s_j[node] = b; }
}

// K2: coarse-bucket histogram (LDS-local, then one global atomic per bin per block)
__global__ void __launch_bounds__(256) k_bhist(const int* __restrict__ dsts,
                                               int* __restrict__ bcnt) {
    __shared__ int h[NBUCK];
    int tid = threadIdx.x;
    for (int b = tid; b < NBUCK; b += 256) h[b] = 0;
    __syncthreads();
    int e0 = blockIdx.x * ECHUNK;
    int e1 = min(e0 + ECHUNK, N_EDGES);
    for (int e = e0 + tid; e < e1; e += 256)
        atomicAdd(&h[dsts[e] >> 8], 1);
    __syncthreads();
    for (int b = tid; b < NBUCK; b += 256)
        if (h[b]) atomicAdd(&bcnt[b], h[b]);
}

// K3: exclusive scan of the 391 bucket counts (single block); init cursors
__global__ void __launch_bounds__(512) k_bscan(const int* __restrict__ bcnt,
                                               int* __restrict__ boffs,
                                               int* __restrict__ bcursor) {
    __shared__ int sh[512];
    int tid = threadIdx.x;
    int v = (tid < NBUCK) ? bcnt[tid] : 0;
    sh[tid] = v;
    __syncthreads();
    for (int off = 1; off < 512; off <<= 1) {
        int t = (tid >= off) ? sh[tid - off] : 0;
        __syncthreads();
        sh[tid] += t;
        __syncthreads();
    }
    if (tid < NBUCK) {
        int o = sh[tid] - v;
        boffs[tid] = o;
        bcursor[tid] = o;
    }
}

// K4: partition edges into coarse buckets. Two passes over the chunk:
//     count per bucket (LDS), reserve one global range per (block,bucket),
//     then re-read edges, compute w = exp(leaky(s_i[dst]+s_j[src])), and write
//     packed {w:32 | dst_local:8 | src:24} in ~10-edge runs per bucket.
__global__ void __launch_bounds__(256) k_partition(const int* __restrict__ srcs,
                                                   const int* __restrict__ dsts,
                                                   const float* __restrict__ s_i,
                                                   const float* __restrict__ s_j,
                                                   int* __restrict__ bcursor,
                                                   uint64_t* __restrict__ pairs) {
    __shared__ int lcnt[NBUCK];
    __shared__ int lbase[NBUCK];
    int tid = threadIdx.x;
    for (int b = tid; b < NBUCK; b += 256) lcnt[b] = 0;
    __syncthreads();
    int e0 = blockIdx.x * ECHUNK;
    int e1 = min(e0 + ECHUNK, N_EDGES);
    for (int e = e0 + tid; e < e1; e += 256)
        atomicAdd(&lcnt[dsts[e] >> 8], 1);
    __syncthreads();
    for (int b = tid; b < NBUCK; b += 256) {
        int c = lcnt[b];
        lbase[b] = c ? atomicAdd(&bcursor[b], c) : 0;
        lcnt[b] = 0;                      // reuse as rank counter
    }
    __syncthreads();
    for (int e = e0 + tid; e < e1; e += 256) {
        int src = srcs[e];
        int dst = dsts[e];
        float sc = s_i[dst] + s_j[src];
        sc = (sc > 0.f) ? sc : SLOPE * sc;
        float w = __expf(sc);
        int b = dst >> 8;
        int r = atomicAdd(&lcnt[b], 1);
        pairs[lbase[b] + r] =
            ((uint64_t)__float_as_uint(w) << 32) |
            ((uint32_t)(dst & 255) << 24) | (uint32_t)src;
    }
}

// K5: one block per 64 nodes (sub-bucket). Scan the owning coarse bucket's
//     region (L2-hot, coalesced), build a per-node sorted pair list in LDS,
//     then per-wave per-node register accumulation with 8x-unrolled gathers.
__global__ void __launch_bounds__(256) k_bucket_agg(const float* __restrict__ x,
                                                    const uint64_t* __restrict__ pairs,
                                                    const int* __restrict__ boffs,
                                                    const int* __restrict__ bcnt,
                                                    float* __restrict__ out) {
    __shared__ uint64_t spairs[CAP];
    __shared__ int scnt[64], soff[64], scnt2[64];
    __shared__ int sovf;
    int tid = threadIdx.x;
    int g = blockIdx.x;                   // 64 nodes per block
    int cb = g >> 2, sub = g & 3;
    int node0 = g * 64;
    const uint64_t* reg = pairs + boffs[cb];
    int rcnt = bcnt[cb];
    if (tid < 64) { scnt[tid] = 0; scnt2[tid] = 0; }
    if (tid == 0) sovf = 0;
    __syncthreads();
    // pass A: per-node degree count for this sub-bucket
    for (int e = tid; e < rcnt; e += 256) {
        int dstl = (int)(((uint32_t)reg[e]) >> 24);
        if ((dstl >> 6) == sub) atomicAdd(&scnt[dstl & 63], 1);
    }
    __syncthreads();
    // exclusive scan of 64 counts (wave 0, shfl)
    if (tid < 64) {
        int v = scnt[tid], s = v;
        for (int o = 1; o < 64; o <<= 1) {
            int t = __shfl_up(s, o, 64);
            if (tid >= o) s += t;
        }
        soff[tid] = s - v;
        if (tid == 63 && s > CAP) sovf = 1;
    }
    __syncthreads();
    int ovf = sovf;
    if (!ovf) {
        // pass B: LDS scatter into per-node sorted order
        for (int e = tid; e < rcnt; e += 256) {
            uint64_t p = reg[e];
            int dstl = (int)(((uint32_t)p) >> 24);
            if ((dstl >> 6) == sub) {
                int n = dstl & 63;
                int r = atomicAdd(&scnt2[n], 1);
                spairs[soff[n] + r] = p;
            }
        }
    }
    __syncthreads();
    int wave = tid >> 6, lane = tid & 63;
    for (int k = wave; k < 64; k += 4) {
        int node = node0 + k;
        if (node >= N_NODES) break;
        float acc0 = 0.f, acc1 = 0.f, acc2 = 0.f, acc3 = 0.f;
        float acc4 = 0.f, acc5 = 0.f, acc6 = 0.f, acc7 = 0.f;
        float den = 0.f;
        int c = scnt[k];
        if (!ovf) {
            const uint64_t* pp = spairs + soff[k];
            int i = 0;
            for (; i + 8 <= c; i += 8) {
                uint64_t p0 = pp[i+0], p1 = pp[i+1], p2 = pp[i+2], p3 = pp[i+3];
                uint64_t p4 = pp[i+4], p5 = pp[i+5], p6 = pp[i+6], p7 = pp[i+7];
                float w0 = __uint_as_float((uint32_t)(p0 >> 32));
                float w1 = __uint_as_float((uint32_t)(p1 >> 32));
                float w2 = __uint_as_float((uint32_t)(p2 >> 32));
                float w3 = __uint_as_float((uint32_t)(p3 >> 32));
                float w4 = __uint_as_float((uint32_t)(p4 >> 32));
                float w5 = __uint_as_float((uint32_t)(p5 >> 32));
                float w6 = __uint_as_float((uint32_t)(p6 >> 32));
                float w7 = __uint_as_float((uint32_t)(p7 >> 32));
                float x0 = x[((uint32_t)p0 & 0xFFFFFF) * HIDDEN + lane];
                float x1 = x[((uint32_t)p1 & 0xFFFFFF) * HIDDEN + lane];
                float x2 = x[((uint32_t)p2 & 0xFFFFFF) * HIDDEN + lane];
                float x3 = x[((uint32_t)p3 & 0xFFFFFF) * HIDDEN + lane];
                float x4 = x[((uint32_t)p4 & 0xFFFFFF) * HIDDEN + lane];
                float x5 = x[((uint32_t)p5 & 0xFFFFFF) * HIDDEN + lane];
                float x6 = x[((uint32_t)p6 & 0xFFFFFF) * HIDDEN + lane];
                float x7 = x[((uint32_t)p7 & 0xFFFFFF) * HIDDEN + lane];
                den += (w0 + w1 + w2 + w3) + (w4 + w5 + w6 + w7);
                acc0 = fmaf(w0, x0, acc0); acc1 = fmaf(w1, x1, acc1);
                acc2 = fmaf(w2, x2, acc2); acc3 = fmaf(w3, x3, acc3);
                acc4 = fmaf(w4, x4, acc4); acc5 = fmaf(w5, x5, acc5);
                acc6 = fmaf(w6, x6, acc6); acc7 = fmaf(w7, x7, acc7);
            }
            if (i + 4 <= c) {
                uint64_t p0 = pp[i+0], p1 = pp[i+1], p2 = pp[i+2], p3 = pp[i+3];
                float w0 = __uint_as_float((uint32_t)(p0 >> 32));
                float w1 = __uint_as_float((uint32_t)(p1 >> 32));
                float w2 = __uint_as_float((uint32_t)(p2 >> 32));
                float w3 = __uint_as_float((uint32_t)(p3 >> 32));
                float x0 = x[((uint32_t)p0 & 0xFFFFFF) * HIDDEN + lane];
                float x1 = x[((uint32_t)p1 & 0xFFFFFF) * HIDDEN + lane];
                float x2 = x[((uint32_t)p2 & 0xFFFFFF) * HIDDEN + lane];
                float x3 = x[((uint32_t)p3 & 0xFFFFFF) * HIDDEN + lane];
                den += (w0 + w1) + (w2 + w3);
                acc0 = fmaf(w0, x0, acc0); acc1 = fmaf(w1, x1, acc1);
                acc2 = fmaf(w2, x2, acc2); acc3 = fmaf(w3, x3, acc3);
                i += 4;
            }
            for (; i < c; ++i) {
                uint64_t p = pp[i];
                float w = __uint_as_float((uint32_t)(p >> 32));
                den += w;
                acc0 = fmaf(w, x[((uint32_t)p & 0xFFFFFF) * HIDDEN + lane], acc0);
            }
        } else {
            // safe fallback (statistically unreachable): scan whole region
            int sn = (sub << 6) | k;
            for (int e = 0; e < rcnt; ++e) {
                uint64_t p = reg[e];
                int dstl = (int)(((uint32_t)p) >> 24);
                if (dstl == sn) {
                    float w = __uint_as_float((uint32_t)(p >> 32));
                    den += w;
                    acc0 = fmaf(w, x[((uint32_t)p & 0xFFFFFF) * HIDDEN + lane], acc0);
                }
            }
        }
        float acc = ((acc0 + acc1) + (acc2 + acc3)) + ((acc4 + acc5) + (acc6 + acc7));
        float r = (c > 0) ? (acc / den) : 0.f;   // empty segment -> 0 (matches ref)
        out[node * HIDDEN + lane] = fmaxf(r, 0.f);
    }
}

extern "C" void kernel_launch(void* const* d_in, const int* in_sizes, int n_in,
                              void* d_out, int out_size, void* d_ws, size_t ws_size,
                              hipStream_t stream) {
    const float* x   = (const float*)d_in[0];
    const int*   ei  = (const int*)d_in[1];   // [2, E]: row0 = src (ej), row1 = dst (ei)
    const float* w_i = (const float*)d_in[2];
    const float* w_j = (const float*)d_in[3];
    float* out = (float*)d_out;

    char* p = (char*)d_ws;
    float*    s_i     = (float*)p;    p += (size_t)N_NODES * 4;
    float*    s_j     = (float*)p;    p += (size_t)N_NODES * 4;
    int*      bcnt    = (int*)p;      p += 4096;
    int*      boffs   = (int*)p;      p += 4096;
    int*      bcursor = (int*)p;      p += 4096;
    uint64_t* pairs   = (uint64_t*)p; // E * 8 bytes

    const int* srcs = ei;             // edge_index[0]
    const int* dsts = ei + N_EDGES;   // edge_index[1]

    int epb = (N_EDGES + ECHUNK - 1) / ECHUNK;   // 391 edge-chunk blocks
    int nagg = (N_NODES + 63) / 64;              // 1563 aggregate blocks

    k_scores    <<<(N_NODES + 3) / 4, 256, 0, stream>>>(x, w_i, w_j, s_i, s_j, bcnt);
    k_bhist     <<<epb, 256, 0, stream>>>(dsts, bcnt);
    k_bscan     <<<1, 512, 0, stream>>>(bcnt, boffs, bcursor);
    k_partition <<<epb, 256, 0, stream>>>(srcs, dsts, s_i, s_j, bcursor, pairs);
    k_bucket_agg<<<nagg, 256, 0, stream>>>(x, pairs, boffs, bcnt, out);
}

// Round 4
// 187.199 us; speedup vs baseline: 2.1282x; 1.2626x over previous
//
#include <hip/hip_runtime.h>
#include <stdint.h>

#define N_NODES 100000
#define N_EDGES 1600000
#define HIDDEN  64
#define SLOPE   0.01f
#define NBUCK   391     // ceil(N_NODES/256): coarse buckets of 256 dst nodes
#define ECHUNK  4096    // edges per partition block
#define CAP     2048    // LDS staging cap per 64-node sub-bucket (mean 1024, sd 32)

// round-to-nearest-even fp32 -> bf16 (as ushort)
__device__ __forceinline__ unsigned short f2bf(float f) {
    uint32_t u = __float_as_uint(f);
    uint32_t r = u + 0x7FFFu + ((u >> 16) & 1u);
    return (unsigned short)(r >> 16);
}

// K1: per-node scores s_i = x.w_i, s_j = x.w_j (wave per node, lane = dim),
//     bf16 copy of x for the gather phase, and zero the bucket counters.
__global__ void __launch_bounds__(256) k_scores(const float* __restrict__ x,
                                                const float* __restrict__ w_i,
                                                const float* __restrict__ w_j,
                                                float* __restrict__ s_i,
                                                float* __restrict__ s_j,
                                                unsigned short* __restrict__ xb,
                                                int* __restrict__ bcnt) {
    int tid = threadIdx.x;
    int gt  = blockIdx.x * 256 + tid;
    if (gt < NBUCK) bcnt[gt] = 0;
    int node = blockIdx.x * 4 + (tid >> 6);
    int lane = tid & 63;
    if (node >= N_NODES) return;
    float v = x[node * HIDDEN + lane];
    xb[node * HIDDEN + lane] = f2bf(v);
    float a = v * w_i[lane];
    float b = v * w_j[lane];
    for (int off = 32; off > 0; off >>= 1) {
        a += __shfl_xor(a, off, 64);
        b += __shfl_xor(b, off, 64);
    }
    if (lane == 0) { s_i[node] = a; s_j[node] = b; }
}

// K2: coarse-bucket histogram (LDS-local, then one global atomic per bin per block)
__global__ void __launch_bounds__(256) k_bhist(const int* __restrict__ dsts,
                                               int* __restrict__ bcnt) {
    __shared__ int h[NBUCK];
    int tid = threadIdx.x;
    for (int b = tid; b < NBUCK; b += 256) h[b] = 0;
    __syncthreads();
    int e0 = blockIdx.x * ECHUNK;
    int e1 = min(e0 + ECHUNK, N_EDGES);
    for (int e = e0 + tid; e < e1; e += 256)
        atomicAdd(&h[dsts[e] >> 8], 1);
    __syncthreads();
    for (int b = tid; b < NBUCK; b += 256)
        if (h[b]) atomicAdd(&bcnt[b], h[b]);
}

// K3: exclusive scan of the 391 bucket counts (single block); init cursors
__global__ void __launch_bounds__(512) k_bscan(const int* __restrict__ bcnt,
                                               int* __restrict__ boffs,
                                               int* __restrict__ bcursor) {
    __shared__ int sh[512];
    int tid = threadIdx.x;
    int v = (tid < NBUCK) ? bcnt[tid] : 0;
    sh[tid] = v;
    __syncthreads();
    for (int off = 1; off < 512; off <<= 1) {
        int t = (tid >= off) ? sh[tid - off] : 0;
        __syncthreads();
        sh[tid] += t;
        __syncthreads();
    }
    if (tid < NBUCK) {
        int o = sh[tid] - v;
        boffs[tid] = o;
        bcursor[tid] = o;
    }
}

// K4: partition edges into coarse buckets, writing packed {dstl:8, src:24}
//     (4B/edge, pure int — w is computed later in the agg staging pass).
__global__ void __launch_bounds__(256) k_partition(const int* __restrict__ srcs,
                                                   const int* __restrict__ dsts,
                                                   int* __restrict__ bcursor,
                                                   uint32_t* __restrict__ pairs) {
    __shared__ int lcnt[NBUCK];
    __shared__ int lbase[NBUCK];
    int tid = threadIdx.x;
    for (int b = tid; b < NBUCK; b += 256) lcnt[b] = 0;
    __syncthreads();
    int e0 = blockIdx.x * ECHUNK;
    int e1 = min(e0 + ECHUNK, N_EDGES);
    for (int e = e0 + tid; e < e1; e += 256)
        atomicAdd(&lcnt[dsts[e] >> 8], 1);
    __syncthreads();
    for (int b = tid; b < NBUCK; b += 256) {
        int c = lcnt[b];
        lbase[b] = c ? atomicAdd(&bcursor[b], c) : 0;
        lcnt[b] = 0;                      // reuse as rank counter
    }
    __syncthreads();
    for (int e = e0 + tid; e < e1; e += 256) {
        int src = srcs[e];
        int dst = dsts[e];
        int b = dst >> 8;
        int r = atomicAdd(&lcnt[b], 1);
        pairs[lbase[b] + r] = ((uint32_t)(dst & 255) << 24) | (uint32_t)src;
    }
}

// K5: one block per 64 nodes. Scan the coarse bucket region (L2-hot),
//     compute w during LDS staging, sort per node, then per-wave per-node
//     register accumulation with 8x-unrolled bf16 gathers.
__global__ void __launch_bounds__(256) k_bucket_agg(const unsigned short* __restrict__ xb,
                                                    const uint32_t* __restrict__ pairs,
                                                    const int* __restrict__ boffs,
                                                    const int* __restrict__ bcnt,
                                                    const float* __restrict__ s_i,
                                                    const float* __restrict__ s_j,
                                                    float* __restrict__ out) {
    __shared__ uint64_t spairs[CAP];
    __shared__ int scnt[64], soff[64], scnt2[64];
    __shared__ float s_si[64];
    __shared__ int sovf;
    int tid = threadIdx.x;
    int g = blockIdx.x;                   // 64 nodes per block
    int cb = g >> 2, sub = g & 3;
    int node0 = g * 64;
    const uint32_t* reg = pairs + boffs[cb];
    int rcnt = bcnt[cb];
    if (tid < 64) {
        scnt[tid] = 0; scnt2[tid] = 0;
        int node = node0 + tid;
        s_si[tid] = (node < N_NODES) ? s_i[node] : 0.f;
    }
    if (tid == 0) sovf = 0;
    __syncthreads();
    // pass A: per-node degree count for this sub-bucket
    for (int e = tid; e < rcnt; e += 256) {
        int dstl = (int)(reg[e] >> 24);
        if ((dstl >> 6) == sub) atomicAdd(&scnt[dstl & 63], 1);
    }
    __syncthreads();
    // exclusive scan of 64 counts (wave 0, shfl)
    if (tid < 64) {
        int v = scnt[tid], s = v;
        for (int o = 1; o < 64; o <<= 1) {
            int t = __shfl_up(s, o, 64);
            if (tid >= o) s += t;
        }
        soff[tid] = s - v;
        if (tid == 63 && s > CAP) sovf = 1;
    }
    __syncthreads();
    int ovf = sovf;
    if (!ovf) {
        // pass B: compute w = exp(leaky(s_i+s_j)), scatter {w,src} per node
        for (int e = tid; e < rcnt; e += 256) {
            uint32_t p = reg[e];
            int dstl = (int)(p >> 24);
            if ((dstl >> 6) == sub) {
                int n = dstl & 63;
                int src = (int)(p & 0xFFFFFFu);
                float sc = s_si[n] + s_j[src];
                sc = (sc > 0.f) ? sc : SLOPE * sc;
                float w = __expf(sc);
                int r = atomicAdd(&scnt2[n], 1);
                spairs[soff[n] + r] =
                    ((uint64_t)__float_as_uint(w) << 32) | (uint32_t)src;
            }
        }
    }
    __syncthreads();
    int wave = tid >> 6, lane = tid & 63;
    for (int k = wave; k < 64; k += 4) {
        int node = node0 + k;
        if (node >= N_NODES) break;
        float acc0 = 0.f, acc1 = 0.f, acc2 = 0.f, acc3 = 0.f;
        float acc4 = 0.f, acc5 = 0.f, acc6 = 0.f, acc7 = 0.f;
        float den = 0.f;
        int c = scnt[k];
        if (!ovf) {
            const uint64_t* pp = spairs + soff[k];
            int i = 0;
            for (; i + 8 <= c; i += 8) {
                uint64_t p0 = pp[i+0], p1 = pp[i+1], p2 = pp[i+2], p3 = pp[i+3];
                uint64_t p4 = pp[i+4], p5 = pp[i+5], p6 = pp[i+6], p7 = pp[i+7];
                float w0 = __uint_as_float((uint32_t)(p0 >> 32));
                float w1 = __uint_as_float((uint32_t)(p1 >> 32));
                float w2 = __uint_as_float((uint32_t)(p2 >> 32));
                float w3 = __uint_as_float((uint32_t)(p3 >> 32));
                float w4 = __uint_as_float((uint32_t)(p4 >> 32));
                float w5 = __uint_as_float((uint32_t)(p5 >> 32));
                float w6 = __uint_as_float((uint32_t)(p6 >> 32));
                float w7 = __uint_as_float((uint32_t)(p7 >> 32));
                float x0 = __uint_as_float((uint32_t)xb[((uint32_t)p0 & 0xFFFFFF) * HIDDEN + lane] << 16);
                float x1 = __uint_as_float((uint32_t)xb[((uint32_t)p1 & 0xFFFFFF) * HIDDEN + lane] << 16);
                float x2 = __uint_as_float((uint32_t)xb[((uint32_t)p2 & 0xFFFFFF) * HIDDEN + lane] << 16);
                float x3 = __uint_as_float((uint32_t)xb[((uint32_t)p3 & 0xFFFFFF) * HIDDEN + lane] << 16);
                float x4 = __uint_as_float((uint32_t)xb[((uint32_t)p4 & 0xFFFFFF) * HIDDEN + lane] << 16);
                float x5 = __uint_as_float((uint32_t)xb[((uint32_t)p5 & 0xFFFFFF) * HIDDEN + lane] << 16);
                float x6 = __uint_as_float((uint32_t)xb[((uint32_t)p6 & 0xFFFFFF) * HIDDEN + lane] << 16);
                float x7 = __uint_as_float((uint32_t)xb[((uint32_t)p7 & 0xFFFFFF) * HIDDEN + lane] << 16);
                den += (w0 + w1 + w2 + w3) + (w4 + w5 + w6 + w7);
                acc0 = fmaf(w0, x0, acc0); acc1 = fmaf(w1, x1, acc1);
                acc2 = fmaf(w2, x2, acc2); acc3 = fmaf(w3, x3, acc3);
                acc4 = fmaf(w4, x4, acc4); acc5 = fmaf(w5, x5, acc5);
                acc6 = fmaf(w6, x6, acc6); acc7 = fmaf(w7, x7, acc7);
            }
            if (i + 4 <= c) {
                uint64_t p0 = pp[i+0], p1 = pp[i+1], p2 = pp[i+2], p3 = pp[i+3];
                float w0 = __uint_as_float((uint32_t)(p0 >> 32));
                float w1 = __uint_as_float((uint32_t)(p1 >> 32));
                float w2 = __uint_as_float((uint32_t)(p2 >> 32));
                float w3 = __uint_as_float((uint32_t)(p3 >> 32));
                float x0 = __uint_as_float((uint32_t)xb[((uint32_t)p0 & 0xFFFFFF) * HIDDEN + lane] << 16);
                float x1 = __uint_as_float((uint32_t)xb[((uint32_t)p1 & 0xFFFFFF) * HIDDEN + lane] << 16);
                float x2 = __uint_as_float((uint32_t)xb[((uint32_t)p2 & 0xFFFFFF) * HIDDEN + lane] << 16);
                float x3 = __uint_as_float((uint32_t)xb[((uint32_t)p3 & 0xFFFFFF) * HIDDEN + lane] << 16);
                den += (w0 + w1) + (w2 + w3);
                acc0 = fmaf(w0, x0, acc0); acc1 = fmaf(w1, x1, acc1);
                acc2 = fmaf(w2, x2, acc2); acc3 = fmaf(w3, x3, acc3);
                i += 4;
            }
            for (; i < c; ++i) {
                uint64_t p = pp[i];
                float w = __uint_as_float((uint32_t)(p >> 32));
                den += w;
                acc0 = fmaf(w, __uint_as_float((uint32_t)xb[((uint32_t)p & 0xFFFFFF) * HIDDEN + lane] << 16), acc0);
            }
        } else {
            // safe fallback (statistically unreachable): scan whole region
            int sn = (sub << 6) | k;
            for (int e = 0; e < rcnt; ++e) {
                uint32_t p = reg[e];
                if ((int)(p >> 24) == sn) {
                    int src = (int)(p & 0xFFFFFFu);
                    float sc = s_si[k] + s_j[src];
                    sc = (sc > 0.f) ? sc : SLOPE * sc;
                    float w = __expf(sc);
                    den += w;
                    acc0 = fmaf(w, __uint_as_float((uint32_t)xb[src * HIDDEN + lane] << 16), acc0);
                }
            }
        }
        float acc = ((acc0 + acc1) + (acc2 + acc3)) + ((acc4 + acc5) + (acc6 + acc7));
        float r = (c > 0) ? (acc / den) : 0.f;   // empty segment -> 0 (matches ref)
        out[node * HIDDEN + lane] = fmaxf(r, 0.f);
    }
}

extern "C" void kernel_launch(void* const* d_in, const int* in_sizes, int n_in,
                              void* d_out, int out_size, void* d_ws, size_t ws_size,
                              hipStream_t stream) {
    const float* x   = (const float*)d_in[0];
    const int*   ei  = (const int*)d_in[1];   // [2, E]: row0 = src (ej), row1 = dst (ei)
    const float* w_i = (const float*)d_in[2];
    const float* w_j = (const float*)d_in[3];
    float* out = (float*)d_out;

    char* p = (char*)d_ws;
    float*          s_i     = (float*)p;          p += (size_t)N_NODES * 4;
    float*          s_j     = (float*)p;          p += (size_t)N_NODES * 4;
    unsigned short* xb      = (unsigned short*)p; p += (size_t)N_NODES * HIDDEN * 2;
    int*            bcnt    = (int*)p;            p += 4096;
    int*            boffs   = (int*)p;            p += 4096;
    int*            bcursor = (int*)p;            p += 4096;
    uint32_t*       pairs   = (uint32_t*)p;       // E * 4 bytes

    const int* srcs = ei;             // edge_index[0]
    const int* dsts = ei + N_EDGES;   // edge_index[1]

    int epb = (N_EDGES + ECHUNK - 1) / ECHUNK;   // 391 edge-chunk blocks
    int nagg = (N_NODES + 63) / 64;              // 1563 aggregate blocks

    k_scores    <<<(N_NODES + 3) / 4, 256, 0, stream>>>(x, w_i, w_j, s_i, s_j, xb, bcnt);
    k_bhist     <<<epb, 256, 0, stream>>>(dsts, bcnt);
    k_bscan     <<<1, 512, 0, stream>>>(bcnt, boffs, bcursor);
    k_partition <<<epb, 256, 0, stream>>>(srcs, dsts, bcursor, pairs);
    k_bucket_agg<<<nagg, 256, 0, stream>>>(xb, pairs, boffs, bcnt, s_i, s_j, out);
}